// Round 5
// baseline (467.083 us; speedup 1.0000x reference)
//
#include <hip/hip_runtime.h>
#include <hip/hip_bf16.h>

#define UHG_EPS 1e-9
#define ZDIM 128

#define EDGE_BLOCKS 1024   // fallback gather path
#define NODE_BLOCKS 1024   // fallback only
#define BLOCK 256

// ---- binned path geometry ----
#define PART_SHIFT 13               // 8192 nodes per partition (64 KB of float2)
#define PART_SIZE (1 << PART_SHIFT)
#define P_MAX 25                    // 25*8192 = 204800 >= 200000
#define NBINS_MAX (P_MAX * P_MAX)   // 625
#define SCAT_BLOCKS 256             // 1 block/CU
#define SBLOCK 512                  // 8 waves/block
#define NWAVES (SBLOCK / 64)
#define SDEPTH 4                    // wave-private staged entries per bin (16 B chunk)
#define BBLOCK 1024                 // binned-edge block: 16 waves
#define SENTINEL 0xFFFFFFFFu
#define OVGUARD 1024                // overflow entries per bin (top region)
#define GPAD 16                     // u32 stride between cursors (one 64B line each)

// ws layout:
//   [0      , 16 KB ) : double prox partials (2*nbins or EDGE_BLOCKS entries)
//   [16 KB  , 32 KB ) : double comp partials (2048 scatter waves / NODE_BLOCKS)
//   [32 KB  , 112 KB) : u32 cursors, line-padded: bottom[b]=gcur[b*16], top[b]=gcur[(nbins+b)*16]
//   [128 KB , +N*8  ) : float2 table[N] (compact x,y per node)
//   [ ...           ) : u32 gbins[nbins][bincap] (routed packed edges)
#define PROX_OFF 0
#define COMP_OFF (16 * 1024)
#define GCUR_OFF (32 * 1024)
#define TABLE_OFF (128 * 1024)

typedef float vfloat2 __attribute__((ext_vector_type(2)));
typedef int vint4 __attribute__((ext_vector_type(4)));
typedef unsigned uvec4 __attribute__((ext_vector_type(4)));

// CK-style asm-declared buffer load (fallback gather path).
__device__ vfloat2 llvm_amdgcn_raw_buffer_load_v2f32(vint4 rsrc, int voffset, int soffset,
                                                     int cpol) __asm("llvm.amdgcn.raw.buffer.load.v2f32");

__device__ __forceinline__ vint4 make_srd(const void* base, unsigned int bytes) {
    union { const void* p; unsigned int w[2]; } pb;
    pb.p = base;
    vint4 r;
    r.x = (int)pb.w[0];
    r.y = (int)pb.w[1];
    r.z = (int)bytes;
    r.w = 0x00020000;
    return r;
}

// ---------------- device helpers ----------------

__device__ __forceinline__ double safe_den(double den) {
    return copysign(fmax(fabs(den), UHG_EPS), den);
}

__device__ __forceinline__ double quad_xy(vfloat2 a, vfloat2 b) {
    double xa = a.x, ya = a.y, xb = b.x, yb = b.y;
    double aa = 1.0 - (xa * xa + ya * ya);
    double bb = 1.0 - (xb * xb + yb * yb);
    double ab = 1.0 - (xa * xb + ya * yb);
    double den = aa * bb;
    double num = ab * ab - den;
    return num / safe_den(den);
}

__device__ __forceinline__ double wave_reduce(double v) {
    v += __shfl_down(v, 32);
    v += __shfl_down(v, 16);
    v += __shfl_down(v, 8);
    v += __shfl_down(v, 4);
    v += __shfl_down(v, 2);
    v += __shfl_down(v, 1);
    return v;
}

// Block reduction for up to 16 waves: returns total on thread 0. sh >= 16 doubles.
__device__ __forceinline__ double block_reduce(double v, double* sh) {
    int lane = threadIdx.x & 63;
    int wid = threadIdx.x >> 6;
    v = wave_reduce(v);
    if (lane == 0) sh[wid] = v;
    __syncthreads();
    double r = 0.0;
    if (wid == 0) {
        int nw = (int)(blockDim.x >> 6);
        r = (lane < nw) ? sh[lane] : 0.0;
        r += __shfl_down(r, 8);
        r += __shfl_down(r, 4);
        r += __shfl_down(r, 2);
        r += __shfl_down(r, 1);
    }
    __syncthreads();
    return r;
}

// ---------------- kernels ----------------

// Fallback-path node kernel (binned path builds the table inside scatter_kernel).
__global__ __launch_bounds__(BLOCK) void node_kernel(const float* __restrict__ z,
                                                     vfloat2* __restrict__ table,
                                                     double* __restrict__ comp_partials, int N) {
    __shared__ double sh[16];
    const vfloat2* zp = (const vfloat2*)z;
    double local = 0.0;
    for (int i = blockIdx.x * BLOCK + threadIdx.x; i < N; i += NODE_BLOCKS * BLOCK) {
        vfloat2 v = zp[(size_t)i * (ZDIM / 2)];
        if (table) table[i] = v;
        double x = v.x, y = v.y;
        double aa = 1.0 - (x * x + y * y);
        local += (1.0 - aa) / safe_den(aa);   // ab=1, bb=1 against origin
    }
    double tot = block_reduce(local, sh);
    if (threadIdx.x == 0) comp_partials[blockIdx.x] = tot;
}

// Phase A v4: wave-autonomous routing — ZERO barriers in the main loop.
// Each wave owns stage[wid][bin][0..3] + cnt[wid][bin] (private -> wave-ordered
// DS ops make insert/flush race-free). Per 4-edge step: 4 LDS atomics on private
// counters, 4 staged stores (slot>=4 -> rare direct overflow append), then every
// lane scans its ~10 bins and flushes any full 16B chunk (vectorized divergent
// flush: ds_read_b128 + global atomic + dwordx4 store, cnt reset to 0).
// Prologue: fused table build + compactness partial per wave (replaces node_kernel).
// Epilogue: one __syncthreads, then block-level residue merge (sentinel-padded).
__global__ __launch_bounds__(SBLOCK) void scatter_kernel(const float* __restrict__ z,
                                                         vfloat2* __restrict__ table,
                                                         double* __restrict__ comp_partials,
                                                         int N,
                                                         const int* __restrict__ src,
                                                         const int* __restrict__ dst, int E,
                                                         int P, int nbins,
                                                         unsigned* __restrict__ gcur,
                                                         unsigned* __restrict__ gbins,
                                                         int bincap) {
    __shared__ unsigned cnt[NWAVES][NBINS_MAX];                      // 20 KB
    __shared__ __align__(16) unsigned stage[NWAVES][NBINS_MAX][SDEPTH];  // 80 KB
    const int tid = threadIdx.x;
    const int lane = tid & 63;
    const int wid = tid >> 6;
    const int TOTW = SCAT_BLOCKS * NWAVES;
    const int gw = blockIdx.x * NWAVES + wid;
    const unsigned botlim = (unsigned)(bincap - OVGUARD);

    for (int b = tid; b < nbins; b += SBLOCK) {
#pragma unroll
        for (int w = 0; w < NWAVES; ++w) cnt[w][b] = 0u;
    }
    // no barrier needed: each wave only touches cnt[wid][*], zeroed by strided
    // threads of all waves... (tid covers all b for every w) -> must sync once.
    __syncthreads();

    // ---- fused table build + compactness (wave slice, no barriers) ----
    {
        const vfloat2* zp = (const vfloat2*)z;
        long n0 = (long)gw * N / TOTW, n1 = (long)(gw + 1) * N / TOTW;
        double comp = 0.0;
        for (long i = n0 + lane; i < n1; i += 64) {
            vfloat2 v = zp[(size_t)i * (ZDIM / 2)];
            table[i] = v;
            double x = v.x, y = v.y;
            double aa = 1.0 - (x * x + y * y);
            comp += (1.0 - aa) / safe_den(aa);
        }
        comp = wave_reduce(comp);
        if (lane == 0) comp_partials[gw] = comp;
    }

    auto ovf = [&](int b, unsigned v) {
        unsigned hp = atomicAdd(&gcur[(size_t)(nbins + b) * GPAD], 1u);
        if (hp < (unsigned)OVGUARD)
            gbins[(size_t)b * bincap + (bincap - 1 - (int)hp)] = v;
    };
    auto insert = [&](int s, int d) {
        int bn = (s >> PART_SHIFT) * P + (d >> PART_SHIFT);
        unsigned vl = (unsigned)(s & (PART_SIZE - 1)) |
                      ((unsigned)(d & (PART_SIZE - 1)) << PART_SHIFT);
        unsigned slot = atomicAdd(&cnt[wid][bn], 1u);
        if (slot < (unsigned)SDEPTH) stage[wid][bn][slot] = vl;
        else ovf(bn, vl);            // P ~ 1e-5 per wave-step per bin
    };
    auto scan_flush = [&]() {
        for (int b = lane; b < nbins; b += 64) {
            if (cnt[wid][b] >= (unsigned)SDEPTH) {
                uvec4 val = *(const uvec4*)&stage[wid][b][0];
                unsigned pos = atomicAdd(&gcur[(size_t)b * GPAD], (unsigned)SDEPTH);
                if (pos + SDEPTH <= botlim) {
                    *(uvec4*)(gbins + (size_t)b * bincap + pos) = val;
                } else {
                    ovf(b, val.x); ovf(b, val.y); ovf(b, val.z); ovf(b, val.w);
                }
                cnt[wid][b] = 0u;
            }
        }
    };

    // ---- wave-contiguous edge range (vint4 granules) ----
    const long nv4 = (long)E / 4;
    long v0 = (long)gw * nv4 / TOTW, v1 = (long)(gw + 1) * nv4 / TOTW;
    const vint4* s4 = (const vint4*)src;
    const vint4* d4 = (const vint4*)dst;

    long niter = (v1 - v0 + 63) >> 6;
    long i = v0 + lane;
    vint4 cs = {}, cd = {};
    if (i < v1) {
        cs = __builtin_nontemporal_load(s4 + i);
        cd = __builtin_nontemporal_load(d4 + i);
    }
    for (long k = 0; k < niter; ++k) {
        bool valid = i < v1;
        vint4 s = cs, d = cd;
        long inext = i + 64;
        if (inext < v1) {
            cs = __builtin_nontemporal_load(s4 + inext);
            cd = __builtin_nontemporal_load(d4 + inext);
        }
        __builtin_amdgcn_sched_barrier(0);
        if (valid) {
            insert(s.x, d.x);
            insert(s.y, d.y);
            insert(s.z, d.z);
            insert(s.w, d.w);
        }
        scan_flush();   // all 64 lanes participate every step
        i = inext;
    }
    // global tail edges (E % 4) handled by the last wave
    if (gw == TOTW - 1) {
        for (long e = 4 * nv4 + lane; e < E; e += 64) insert(src[e], dst[e]);
        scan_flush();
    }

    // ---- block-level residue merge (the only barrier of the main path) ----
    __syncthreads();
    for (int b = tid; b < nbins; b += SBLOCK) {
        unsigned buf[SDEPTH];
        int m = 0;
        for (int w = 0; w < NWAVES; ++w) {
            unsigned n = cnt[w][b];
            if (n > (unsigned)SDEPTH) n = (unsigned)SDEPTH;   // extras already ovf'd
            for (unsigned j = 0; j < n; ++j) {
                buf[m++] = stage[w][b][j];
                if (m == SDEPTH) {
                    unsigned pos = atomicAdd(&gcur[(size_t)b * GPAD], (unsigned)SDEPTH);
                    if (pos + SDEPTH <= botlim) {
                        uvec4 v4v = {buf[0], buf[1], buf[2], buf[3]};
                        *(uvec4*)(gbins + (size_t)b * bincap + pos) = v4v;
                    } else {
                        for (int j2 = 0; j2 < SDEPTH; ++j2) ovf(b, buf[j2]);
                    }
                    m = 0;
                }
            }
        }
        if (m > 0) {
            for (int j = m; j < SDEPTH; ++j) buf[j] = SENTINEL;
            unsigned pos = atomicAdd(&gcur[(size_t)b * GPAD], (unsigned)SDEPTH);
            if (pos + SDEPTH <= botlim) {
                uvec4 v4v = {buf[0], buf[1], buf[2], buf[3]};
                *(uvec4*)(gbins + (size_t)b * bincap + pos) = v4v;
            } else {
                for (int j2 = 0; j2 < m; ++j2) ovf(b, buf[j2]);
            }
        }
    }
}

// Phase B v3: TWO blocks per bin (grid 2*nbins -> 4.88 rounds over 256 CUs,
// tail idle ~2.5% instead of 23%). Both endpoint partitions in LDS (128 KB);
// uint4 payload stream software-pipelined one iteration ahead.
__global__ __launch_bounds__(BBLOCK) void binned_edge_kernel(const vfloat2* __restrict__ table,
                                                             int N, int P,
                                                             const unsigned* __restrict__ gcur,
                                                             const unsigned* __restrict__ gbins,
                                                             int bincap,
                                                             double* __restrict__ prox_partials) {
    __shared__ vfloat2 pts[2][PART_SIZE];   // 128 KB
    __shared__ double sh[16];
    const int bin = blockIdx.x >> 1;
    const int half = blockIdx.x & 1;
    const int sp = bin / P, dp = bin % P;
    const int tid = threadIdx.x;
    const int nbins = P * P;
    const unsigned botlim = (unsigned)(bincap - OVGUARD);

    for (int j = tid; j < PART_SIZE; j += BBLOCK) {
        int gs = (sp << PART_SHIFT) + j;
        int gd = (dp << PART_SHIFT) + j;
        vfloat2 zv = {0.0f, 0.0f};
        pts[0][j] = (gs < N) ? table[gs] : zv;
        pts[1][j] = (gd < N) ? table[gd] : zv;
    }
    __syncthreads();

    unsigned lo = gcur[(size_t)bin * GPAD];
    if (lo > botlim) lo = botlim;
    unsigned hi = gcur[(size_t)(nbins + bin) * GPAD];
    if (hi > (unsigned)OVGUARD) hi = (unsigned)OVGUARD;
    const unsigned* eb = gbins + (size_t)bin * bincap;

    unsigned h0 = (lo >> 1) & ~3u;                   // 16B-aligned split point
    unsigned rs = half ? h0 : 0u;
    unsigned re = half ? lo : h0;

    double local = 0.0;
    unsigned ng = (re - rs) >> 2;                    // full uint4 groups
    const uvec4* eb4 = (const uvec4*)(eb + rs);
    unsigned i = tid;
    bool have = i < ng;
    uvec4 cur = {};
    if (have) cur = __builtin_nontemporal_load(eb4 + i);
    while (have) {
        unsigned in2 = i + BBLOCK;
        bool hn = in2 < ng;
        uvec4 nxt = {};
        if (hn) nxt = __builtin_nontemporal_load(eb4 + in2);
        __builtin_amdgcn_sched_barrier(0);
        vfloat2 a0 = pts[0][cur.x & (PART_SIZE - 1u)], b0 = pts[1][(cur.x >> PART_SHIFT) & (PART_SIZE - 1u)];
        vfloat2 a1 = pts[0][cur.y & (PART_SIZE - 1u)], b1 = pts[1][(cur.y >> PART_SHIFT) & (PART_SIZE - 1u)];
        vfloat2 a2 = pts[0][cur.z & (PART_SIZE - 1u)], b2 = pts[1][(cur.z >> PART_SHIFT) & (PART_SIZE - 1u)];
        vfloat2 a3 = pts[0][cur.w & (PART_SIZE - 1u)], b3 = pts[1][(cur.w >> PART_SHIFT) & (PART_SIZE - 1u)];
        if (cur.x != SENTINEL) local += quad_xy(a0, b0);
        if (cur.y != SENTINEL) local += quad_xy(a1, b1);
        if (cur.z != SENTINEL) local += quad_xy(a2, b2);
        if (cur.w != SENTINEL) local += quad_xy(a3, b3);
        cur = nxt;
        i = in2;
        have = hn;
    }
    for (unsigned j = rs + (ng << 2) + tid; j < re; j += BBLOCK) {   // tail (half==1 only)
        unsigned v = eb[j];
        if (v != SENTINEL)
            local += quad_xy(pts[0][v & (PART_SIZE - 1u)],
                             pts[1][(v >> PART_SHIFT) & (PART_SIZE - 1u)]);
    }
    if (half) {
        for (unsigned j = tid; j < hi; j += BBLOCK) {   // overflow (top) region
            unsigned v = eb[bincap - 1 - (int)j];
            local += quad_xy(pts[0][v & (PART_SIZE - 1u)],
                             pts[1][(v >> PART_SHIFT) & (PART_SIZE - 1u)]);
        }
    }
    double tot = block_reduce(local, sh);
    if (tid == 0) prox_partials[blockIdx.x] = tot;
}

// -------- fallback gather path (verified round-1 kernel, unchanged) --------
#define GATHER8(dsta, i0, i1)                                                   \
    dsta[0] = llvm_amdgcn_raw_buffer_load_v2f32(srd, (i0).x << SHIFT, 0, 1);    \
    dsta[1] = llvm_amdgcn_raw_buffer_load_v2f32(srd, (i0).y << SHIFT, 0, 1);    \
    dsta[2] = llvm_amdgcn_raw_buffer_load_v2f32(srd, (i0).z << SHIFT, 0, 1);    \
    dsta[3] = llvm_amdgcn_raw_buffer_load_v2f32(srd, (i0).w << SHIFT, 0, 1);    \
    dsta[4] = llvm_amdgcn_raw_buffer_load_v2f32(srd, (i1).x << SHIFT, 0, 1);    \
    dsta[5] = llvm_amdgcn_raw_buffer_load_v2f32(srd, (i1).y << SHIFT, 0, 1);    \
    dsta[6] = llvm_amdgcn_raw_buffer_load_v2f32(srd, (i1).z << SHIFT, 0, 1);    \
    dsta[7] = llvm_amdgcn_raw_buffer_load_v2f32(srd, (i1).w << SHIFT, 0, 1);

template <int COMPACT>
__global__ __launch_bounds__(BLOCK) void edge_kernel(const vint4* __restrict__ src4,
                                                     const vint4* __restrict__ dst4, int nvec,
                                                     const int* __restrict__ src,
                                                     const int* __restrict__ dst, int E,
                                                     const void* __restrict__ xy, int N,
                                                     double* __restrict__ prox_partials) {
    __shared__ double sh[16];
    double local = 0.0;
    int tid = blockIdx.x * BLOCK + threadIdx.x;
    const int gstride = EDGE_BLOCKS * BLOCK;
    const int SHIFT = COMPACT ? 3 : 9;

    vint4 srd = make_srd(xy, COMPACT ? (unsigned int)N * 8u : (unsigned int)N * 512u);

    int nvec2 = nvec / 2;
    int v0 = tid;
    bool p0 = v0 < nvec2;
    int v1 = v0 + gstride;
    bool p1 = v1 < nvec2;

    vint4 is0 = {}, is1 = {}, id0 = {}, id1 = {};
    vfloat2 ca[8] = {}, cb[8] = {};
    vfloat2 na[8] = {}, nb[8] = {};

    if (p0) {
        vint4 s0 = __builtin_nontemporal_load(src4 + 2 * (long)v0);
        vint4 s1 = __builtin_nontemporal_load(src4 + 2 * (long)v0 + 1);
        vint4 d0 = __builtin_nontemporal_load(dst4 + 2 * (long)v0);
        vint4 d1 = __builtin_nontemporal_load(dst4 + 2 * (long)v0 + 1);
        GATHER8(ca, s0, s1);
        GATHER8(cb, d0, d1);
    }
    if (p1) {
        is0 = __builtin_nontemporal_load(src4 + 2 * (long)v1);
        is1 = __builtin_nontemporal_load(src4 + 2 * (long)v1 + 1);
        id0 = __builtin_nontemporal_load(dst4 + 2 * (long)v1);
        id1 = __builtin_nontemporal_load(dst4 + 2 * (long)v1 + 1);
    }

    while (p0) {
        if (p1) {
            GATHER8(na, is0, is1);
            GATHER8(nb, id0, id1);
        }
        int v2 = v1 + gstride;
        bool p2 = v2 < nvec2;
        if (p2) {
            is0 = __builtin_nontemporal_load(src4 + 2 * (long)v2);
            is1 = __builtin_nontemporal_load(src4 + 2 * (long)v2 + 1);
            id0 = __builtin_nontemporal_load(dst4 + 2 * (long)v2);
            id1 = __builtin_nontemporal_load(dst4 + 2 * (long)v2 + 1);
        }
        __builtin_amdgcn_sched_barrier(0);
#pragma unroll
        for (int i = 0; i < 8; ++i) local += quad_xy(ca[i], cb[i]);
#pragma unroll
        for (int i = 0; i < 8; ++i) { ca[i] = na[i]; cb[i] = nb[i]; }
        p0 = p1;
        v1 = v2;
        p1 = p2;
    }

    for (int e = 8 * nvec2 + tid; e < E; e += gstride) {
        vfloat2 a = llvm_amdgcn_raw_buffer_load_v2f32(srd, src[e] << SHIFT, 0, 1);
        vfloat2 b = llvm_amdgcn_raw_buffer_load_v2f32(srd, dst[e] << SHIFT, 0, 1);
        local += quad_xy(a, b);
    }
    double tot = block_reduce(local, sh);
    if (threadIdx.x == 0) prox_partials[blockIdx.x] = tot;
}

// Sum partials + spread over first min(10,E) edges + combine. One block of 256.
__global__ __launch_bounds__(BLOCK) void finalize_kernel(const int* __restrict__ src,
                                                         const int* __restrict__ dst,
                                                         const float* __restrict__ z,
                                                         const double* __restrict__ prox_partials,
                                                         int nprox,
                                                         const double* __restrict__ comp_partials,
                                                         int ncomp,
                                                         float* __restrict__ out, int N, int E) {
    __shared__ double sh[16];
    int t = threadIdx.x;

    double pl = 0.0;
    for (int i = t; i < nprox; i += BLOCK) pl += prox_partials[i];
    double prox = block_reduce(pl, sh);

    double cl = 0.0;
    for (int i = t; i < ncomp; i += BLOCK) cl += comp_partials[i];
    double comp = block_reduce(cl, sh);

    int n_sp = E < 10 ? E : 10;
    double sl = 0.0;
    if (t < n_sp) {
        int s = src[t], d = dst[t];
        double xa = z[(size_t)s * ZDIM], ya = z[(size_t)s * ZDIM + 1];
        double xb = z[(size_t)d * ZDIM], yb = z[(size_t)d * ZDIM + 1];
        double aa = -(ya * ya + xa * xa);
        double bb = -(yb * yb + xb * xb);
        double ab = -(ya * yb + xa * xb);
        double den = aa * bb;
        sl = (ab * ab - den) / safe_den(den);
    }
    double spread = block_reduce(sl, sh);

    if (t == 0) {
        double loss = prox / (double)E + comp / (double)N;
        if (n_sp > 0) loss += 0.1 * (spread / (double)n_sp);
        out[0] = (float)loss;
    }
}

// ---------------- launch ----------------

extern "C" void kernel_launch(void* const* d_in, const int* in_sizes, int n_in,
                              void* d_out, int out_size, void* d_ws, size_t ws_size,
                              hipStream_t stream) {
    const float* z = (const float*)d_in[0];
    const int* edge_index = (const int*)d_in[1];
    float* out = (float*)d_out;

    const int N = in_sizes[0] / ZDIM;
    const int E = in_sizes[1] / 2;
    const int* src = edge_index;
    const int* dst = edge_index + (size_t)E;

    double* prox_partials = (double*)((char*)d_ws + PROX_OFF);
    double* comp_partials = (double*)((char*)d_ws + COMP_OFF);
    unsigned* gcur = (unsigned*)((char*)d_ws + GCUR_OFF);
    vfloat2* table = (vfloat2*)((char*)d_ws + TABLE_OFF);
    bool use_table = ws_size >= TABLE_OFF + (size_t)N * sizeof(vfloat2);

    // binned-path feasibility (ws-adaptive bincap)
    const int P = (N + PART_SIZE - 1) >> PART_SHIFT;
    const int nbins = P * P;
    size_t gbins_off = TABLE_OFF + (((size_t)N * 8 + 255) & ~(size_t)255);
    bool use_binned = false;
    unsigned* gbins = nullptr;
    int bincap = 0;
    if (use_table && P >= 1 && P <= P_MAX && nbins <= NBINS_MAX && E > nbins * 64 &&
        ws_size > gbins_off) {
        int mean = E / nbins;
        // slack: block-merge sentinel pads (<=3 per block-bin, ~1.5 avg * 256)
        //        + ~14 sigma Poisson headroom + OVGUARD top region
        int cap_want = (mean + 768 + 2048 + OVGUARD + 31) & ~31;
        int need_min = mean + 512 + 1024 + OVGUARD;
        size_t avail = ws_size - gbins_off;
        int cap_fit = (int)((avail / ((size_t)nbins * 4)) & ~(size_t)31);
        bincap = cap_fit < cap_want ? cap_fit : cap_want;
        if (bincap >= need_min) {
            use_binned = true;
            gbins = (unsigned*)((char*)d_ws + gbins_off);
        }
    }

    if (use_binned) {
        hipMemsetAsync(gcur, 0, (size_t)2 * nbins * GPAD * sizeof(unsigned), stream);
        scatter_kernel<<<SCAT_BLOCKS, SBLOCK, 0, stream>>>(z, table, comp_partials, N,
                                                           src, dst, E, P, nbins, gcur,
                                                           gbins, bincap);
        binned_edge_kernel<<<2 * nbins, BBLOCK, 0, stream>>>(table, N, P, gcur, gbins, bincap,
                                                             prox_partials);
        finalize_kernel<<<1, BLOCK, 0, stream>>>(src, dst, z, prox_partials, 2 * nbins,
                                                 comp_partials, SCAT_BLOCKS * NWAVES,
                                                 out, N, E);
    } else {
        node_kernel<<<NODE_BLOCKS, BLOCK, 0, stream>>>(z, use_table ? table : nullptr,
                                                       comp_partials, N);
        int nvec = E / 4;
        if (use_table) {
            edge_kernel<1><<<EDGE_BLOCKS, BLOCK, 0, stream>>>((const vint4*)src,
                                                              (const vint4*)dst, nvec, src, dst,
                                                              E, table, N, prox_partials);
        } else {
            edge_kernel<0><<<EDGE_BLOCKS, BLOCK, 0, stream>>>((const vint4*)src,
                                                              (const vint4*)dst, nvec, src, dst,
                                                              E, z, N, prox_partials);
        }
        finalize_kernel<<<1, BLOCK, 0, stream>>>(src, dst, z, prox_partials, EDGE_BLOCKS,
                                                 comp_partials, NODE_BLOCKS, out, N, E);
    }
}

// Round 6
// 281.964 us; speedup vs baseline: 1.6565x; 1.6565x over previous
//
#include <hip/hip_runtime.h>
#include <hip/hip_bf16.h>

#define UHG_EPS 1e-9
#define ZDIM 128

#define EDGE_BLOCKS 1024   // fallback gather path
#define NODE_BLOCKS 1024   // fallback only
#define BLOCK 256

// ---- binned path geometry ----
#define PART_SHIFT 13               // 8192 nodes per partition (64 KB of float2)
#define PART_SIZE (1 << PART_SHIFT)
#define P_MAX 25                    // 25*8192 = 204800 >= 200000
#define NBINS_MAX (P_MAX * P_MAX)   // 625
#define RING 32                     // ring slots per bin (two 64B chunks)
#define CHUNK 16                    // flush granularity: 16 u32 = 64 B (HBM line)
#define SCAT_BLOCKS 256             // 1 block/CU
#define SBLOCK 1024                 // 16 waves/block = 16 waves/CU (same as r4's 2x8)
#define BBLOCK 1024                 // binned-edge block: 16 waves
#define SENTINEL 0xFFFFFFFFu
#define OVGUARD 1024                // overflow entries per bin (top region)
#define GPAD 16                     // u32 stride between cursors (one 64B line each)

// ws layout:
//   [0      , 16 KB ) : double prox partials (2*nbins or EDGE_BLOCKS entries)
//   [16 KB  , 32 KB ) : double comp partials (SCAT_BLOCKS or NODE_BLOCKS)
//   [32 KB  , 112 KB) : u32 cursors, line-padded: bottom[b]=gcur[b*16], top[b]=gcur[(nbins+b)*16]
//   [128 KB , +N*8  ) : float2 table[N] (compact x,y per node)
//   [ ...           ) : u32 gbins[nbins][bincap] (routed packed edges)
#define PROX_OFF 0
#define COMP_OFF (16 * 1024)
#define GCUR_OFF (32 * 1024)
#define TABLE_OFF (128 * 1024)

typedef float vfloat2 __attribute__((ext_vector_type(2)));
typedef int vint4 __attribute__((ext_vector_type(4)));
typedef unsigned uvec4 __attribute__((ext_vector_type(4)));

// CK-style asm-declared buffer load (fallback gather path).
__device__ vfloat2 llvm_amdgcn_raw_buffer_load_v2f32(vint4 rsrc, int voffset, int soffset,
                                                     int cpol) __asm("llvm.amdgcn.raw.buffer.load.v2f32");

__device__ __forceinline__ vint4 make_srd(const void* base, unsigned int bytes) {
    union { const void* p; unsigned int w[2]; } pb;
    pb.p = base;
    vint4 r;
    r.x = (int)pb.w[0];
    r.y = (int)pb.w[1];
    r.z = (int)bytes;
    r.w = 0x00020000;
    return r;
}

// ---------------- device helpers ----------------

__device__ __forceinline__ double safe_den(double den) {
    return copysign(fmax(fabs(den), UHG_EPS), den);
}

__device__ __forceinline__ double quad_xy(vfloat2 a, vfloat2 b) {
    double xa = a.x, ya = a.y, xb = b.x, yb = b.y;
    double aa = 1.0 - (xa * xa + ya * ya);
    double bb = 1.0 - (xb * xb + yb * yb);
    double ab = 1.0 - (xa * xb + ya * yb);
    double den = aa * bb;
    double num = ab * ab - den;
    return num / safe_den(den);
}

__device__ __forceinline__ double wave_reduce(double v) {
    v += __shfl_down(v, 32);
    v += __shfl_down(v, 16);
    v += __shfl_down(v, 8);
    v += __shfl_down(v, 4);
    v += __shfl_down(v, 2);
    v += __shfl_down(v, 1);
    return v;
}

// Block reduction for up to 16 waves: returns total on thread 0. sh >= 16 doubles.
__device__ __forceinline__ double block_reduce(double v, double* sh) {
    int lane = threadIdx.x & 63;
    int wid = threadIdx.x >> 6;
    v = wave_reduce(v);
    if (lane == 0) sh[wid] = v;
    __syncthreads();
    double r = 0.0;
    if (wid == 0) {
        int nw = (int)(blockDim.x >> 6);
        r = (lane < nw) ? sh[lane] : 0.0;
        r += __shfl_down(r, 8);
        r += __shfl_down(r, 4);
        r += __shfl_down(r, 2);
        r += __shfl_down(r, 1);
    }
    __syncthreads();
    return r;
}

// ---------------- kernels ----------------

// Fallback-path node kernel (binned path builds the table inside scatter_kernel).
__global__ __launch_bounds__(BLOCK) void node_kernel(const float* __restrict__ z,
                                                     vfloat2* __restrict__ table,
                                                     double* __restrict__ comp_partials, int N) {
    __shared__ double sh[16];
    const vfloat2* zp = (const vfloat2*)z;
    double local = 0.0;
    for (int i = blockIdx.x * BLOCK + threadIdx.x; i < N; i += NODE_BLOCKS * BLOCK) {
        vfloat2 v = zp[(size_t)i * (ZDIM / 2)];
        if (table) table[i] = v;
        double x = v.x, y = v.y;
        double aa = 1.0 - (x * x + y * y);
        local += (1.0 - aa) / safe_den(aa);   // ab=1, bb=1 against origin
    }
    double tot = block_reduce(local, sh);
    if (threadIdx.x == 0) comp_partials[blockIdx.x] = tot;
}

// Phase A v5 = r4's verified batch-synchronous structure + ring flush.
// Block-shared bins: cnt[b] atomically incremented by inserters; stage[b] is a
// 32-slot ring with sstart[b] in {0,16}. Insert writes (sstart+slot)&31; flush
// copies ONE aligned 64B chunk (4x ds_read_b128 -> 4x dwordx4) and XORs sstart —
// no shift-down. 64B chunks keep HBM writes line-granular (r5's 16B chunks gave
// 4x write amplification: WRITE_SIZE 218MB). Prologue fuses the table build +
// compactness partial (replaces node_kernel on this path).
__global__ __launch_bounds__(SBLOCK) void scatter_kernel(const float* __restrict__ z,
                                                         vfloat2* __restrict__ table,
                                                         double* __restrict__ comp_partials,
                                                         int N,
                                                         const int* __restrict__ src,
                                                         const int* __restrict__ dst, int E,
                                                         int P, int nbins,
                                                         unsigned* __restrict__ gcur,
                                                         unsigned* __restrict__ gbins,
                                                         int bincap) {
    __shared__ unsigned cnt[NBINS_MAX];                        // 2.5 KB
    __shared__ unsigned sstart[NBINS_MAX];                     // 2.5 KB
    __shared__ __align__(16) unsigned stage[NBINS_MAX][RING];  // 80 KB
    __shared__ double sh[16];
    const int tid = threadIdx.x;
    const unsigned botlim = (unsigned)(bincap - OVGUARD);

    for (int b = tid; b < nbins; b += SBLOCK) {
        cnt[b] = 0u;
        sstart[b] = 0u;
    }
    __syncthreads();

    // ---- fused table build + compactness partial (replaces node_kernel) ----
    {
        const vfloat2* zp = (const vfloat2*)z;
        long n0 = (long)blockIdx.x * N / SCAT_BLOCKS;
        long n1 = (long)(blockIdx.x + 1) * N / SCAT_BLOCKS;
        double comp = 0.0;
        for (long i = n0 + tid; i < n1; i += SBLOCK) {
            vfloat2 v = zp[(size_t)i * (ZDIM / 2)];
            table[i] = v;
            double x = v.x, y = v.y;
            double aa = 1.0 - (x * x + y * y);
            comp += (1.0 - aa) / safe_den(aa);
        }
        double tot = block_reduce(comp, sh);   // contains 2 __syncthreads (uniform)
        if (tid == 0) comp_partials[blockIdx.x] = tot;
    }

    auto ovf = [&](int b, unsigned v) {
        unsigned hp = atomicAdd(&gcur[(size_t)(nbins + b) * GPAD], 1u);
        if (hp < (unsigned)OVGUARD)
            gbins[(size_t)b * bincap + (bincap - 1 - (int)hp)] = v;
    };

    // Flush: each of the first nbins threads owns one bin. Ring => copy-free.
    auto flush_bins = [&](bool final_pad) {
        int b = tid;
        if (b < nbins) {
            unsigned n = cnt[b];
            unsigned st = sstart[b];
            unsigned m = n < (unsigned)RING ? n : (unsigned)RING;  // extras already ovf'd
            while (m >= (unsigned)CHUNK) {
                const unsigned* sp = &stage[b][st];                // st in {0,16}: aligned 64B
                uvec4 x0 = *(const uvec4*)(sp + 0);
                uvec4 x1 = *(const uvec4*)(sp + 4);
                uvec4 x2 = *(const uvec4*)(sp + 8);
                uvec4 x3 = *(const uvec4*)(sp + 12);
                unsigned pos = atomicAdd(&gcur[(size_t)b * GPAD], (unsigned)CHUNK);
                if (pos + CHUNK <= botlim) {
                    unsigned* out = gbins + (size_t)b * bincap + pos;
                    *(uvec4*)(out + 0) = x0;
                    *(uvec4*)(out + 4) = x1;
                    *(uvec4*)(out + 8) = x2;
                    *(uvec4*)(out + 12) = x3;
                } else {
                    ovf(b, x0.x); ovf(b, x0.y); ovf(b, x0.z); ovf(b, x0.w);
                    ovf(b, x1.x); ovf(b, x1.y); ovf(b, x1.z); ovf(b, x1.w);
                    ovf(b, x2.x); ovf(b, x2.y); ovf(b, x2.z); ovf(b, x2.w);
                    ovf(b, x3.x); ovf(b, x3.y); ovf(b, x3.z); ovf(b, x3.w);
                }
                st ^= (unsigned)CHUNK;
                m -= (unsigned)CHUNK;
            }
            if (final_pad && m > 0) {
                // residue occupies stage[b][st .. st+m-1] (contiguous, m<16)
                for (unsigned j = m; j < (unsigned)CHUNK; ++j) stage[b][st + j] = SENTINEL;
                const unsigned* sp = &stage[b][st];
                uvec4 x0 = *(const uvec4*)(sp + 0);
                uvec4 x1 = *(const uvec4*)(sp + 4);
                uvec4 x2 = *(const uvec4*)(sp + 8);
                uvec4 x3 = *(const uvec4*)(sp + 12);
                unsigned pos = atomicAdd(&gcur[(size_t)b * GPAD], (unsigned)CHUNK);
                if (pos + CHUNK <= botlim) {
                    unsigned* out = gbins + (size_t)b * bincap + pos;
                    *(uvec4*)(out + 0) = x0;
                    *(uvec4*)(out + 4) = x1;
                    *(uvec4*)(out + 8) = x2;
                    *(uvec4*)(out + 12) = x3;
                } else {
                    for (unsigned j = 0; j < m; ++j) ovf(b, stage[b][st + j]);
                }
                m = 0;
                st = 0;
            }
            cnt[b] = m;
            sstart[b] = st;
        }
    };

    // ---- contiguous per-block edge range in vint4 granules ----
    const long nv4 = (long)E / 4;
    long g0 = (long)blockIdx.x * nv4 / SCAT_BLOCKS;
    long g1 = (long)(blockIdx.x + 1) * nv4 / SCAT_BLOCKS;
    const vint4* s4 = (const vint4*)src;
    const vint4* d4 = (const vint4*)dst;
    long nbatch = (g1 - g0 + SBLOCK - 1) / SBLOCK;

    long i = g0 + tid;
    vint4 cs = {}, cd = {};
    if (i < g1) {
        cs = __builtin_nontemporal_load(s4 + i);
        cd = __builtin_nontemporal_load(d4 + i);
    }
    for (long k = 0; k < nbatch; ++k) {
        bool valid = i < g1;
        vint4 s = cs, d = cd;
        long inext = i + SBLOCK;
        if (inext < g1) {   // prefetch next batch before touching LDS
            cs = __builtin_nontemporal_load(s4 + inext);
            cd = __builtin_nontemporal_load(d4 + inext);
        }
        __builtin_amdgcn_sched_barrier(0);
        if (valid) {
            // phase 1: pure VALU + sstart reads
            int bn0 = (s.x >> PART_SHIFT) * P + (d.x >> PART_SHIFT);
            int bn1 = (s.y >> PART_SHIFT) * P + (d.y >> PART_SHIFT);
            int bn2 = (s.z >> PART_SHIFT) * P + (d.z >> PART_SHIFT);
            int bn3 = (s.w >> PART_SHIFT) * P + (d.w >> PART_SHIFT);
            unsigned vl0 = (unsigned)(s.x & (PART_SIZE - 1)) | ((unsigned)(d.x & (PART_SIZE - 1)) << PART_SHIFT);
            unsigned vl1 = (unsigned)(s.y & (PART_SIZE - 1)) | ((unsigned)(d.y & (PART_SIZE - 1)) << PART_SHIFT);
            unsigned vl2 = (unsigned)(s.z & (PART_SIZE - 1)) | ((unsigned)(d.z & (PART_SIZE - 1)) << PART_SHIFT);
            unsigned vl3 = (unsigned)(s.w & (PART_SIZE - 1)) | ((unsigned)(d.w & (PART_SIZE - 1)) << PART_SHIFT);
            unsigned st0 = sstart[bn0], st1 = sstart[bn1], st2 = sstart[bn2], st3 = sstart[bn3];
            // phase 2: back-to-back ds_add_rtn (pipelined returns)
            unsigned sl0 = atomicAdd(&cnt[bn0], 1u);
            unsigned sl1 = atomicAdd(&cnt[bn1], 1u);
            unsigned sl2 = atomicAdd(&cnt[bn2], 1u);
            unsigned sl3 = atomicAdd(&cnt[bn3], 1u);
            // phase 3: ring placement (capacity overflow P~1e-4 -> top region)
            if (sl0 < (unsigned)RING) stage[bn0][(st0 + sl0) & (RING - 1)] = vl0; else ovf(bn0, vl0);
            if (sl1 < (unsigned)RING) stage[bn1][(st1 + sl1) & (RING - 1)] = vl1; else ovf(bn1, vl1);
            if (sl2 < (unsigned)RING) stage[bn2][(st2 + sl2) & (RING - 1)] = vl2; else ovf(bn2, vl2);
            if (sl3 < (unsigned)RING) stage[bn3][(st3 + sl3) & (RING - 1)] = vl3; else ovf(bn3, vl3);
        }
        __syncthreads();
        flush_bins(false);
        __syncthreads();
        i = inext;
    }
    // global tail edges (E % 4): handled by the last block
    if (blockIdx.x == SCAT_BLOCKS - 1) {
        for (long e = 4 * nv4 + tid; e < E; e += SBLOCK) {
            int s = src[e], d = dst[e];
            int bn = (s >> PART_SHIFT) * P + (d >> PART_SHIFT);
            unsigned vl = (unsigned)(s & (PART_SIZE - 1)) |
                          ((unsigned)(d & (PART_SIZE - 1)) << PART_SHIFT);
            unsigned st = sstart[bn];
            unsigned sl = atomicAdd(&cnt[bn], 1u);
            if (sl < (unsigned)RING) stage[bn][(st + sl) & (RING - 1)] = vl; else ovf(bn, vl);
        }
    }
    __syncthreads();
    flush_bins(true);   // drain + sentinel-pad residues to one full chunk
}

// Phase B v3: TWO blocks per bin (grid 2*nbins = 1250 -> 4.9 rounds over 256 CUs,
// tail idle ~2.5% instead of 23%). Both endpoint partitions in LDS (128 KB);
// uint4 payload stream software-pipelined one iteration ahead. (r4-verified loop.)
__global__ __launch_bounds__(BBLOCK) void binned_edge_kernel(const vfloat2* __restrict__ table,
                                                             int N, int P,
                                                             const unsigned* __restrict__ gcur,
                                                             const unsigned* __restrict__ gbins,
                                                             int bincap,
                                                             double* __restrict__ prox_partials) {
    __shared__ vfloat2 pts[2][PART_SIZE];   // 128 KB
    __shared__ double sh[16];
    const int bin = blockIdx.x >> 1;
    const int half = blockIdx.x & 1;
    const int sp = bin / P, dp = bin % P;
    const int tid = threadIdx.x;
    const int nbins = P * P;
    const unsigned botlim = (unsigned)(bincap - OVGUARD);

    for (int j = tid; j < PART_SIZE; j += BBLOCK) {
        int gs = (sp << PART_SHIFT) + j;
        int gd = (dp << PART_SHIFT) + j;
        vfloat2 zv = {0.0f, 0.0f};
        pts[0][j] = (gs < N) ? table[gs] : zv;
        pts[1][j] = (gd < N) ? table[gd] : zv;
    }
    __syncthreads();

    unsigned lo = gcur[(size_t)bin * GPAD];
    if (lo > botlim) lo = botlim;
    unsigned hi = gcur[(size_t)(nbins + bin) * GPAD];
    if (hi > (unsigned)OVGUARD) hi = (unsigned)OVGUARD;
    const unsigned* eb = gbins + (size_t)bin * bincap;

    unsigned h0 = (lo >> 1) & ~3u;                   // 16B-aligned split point
    unsigned rs = half ? h0 : 0u;
    unsigned re = half ? lo : h0;

    double local = 0.0;
    unsigned ng = (re - rs) >> 2;                    // full uint4 groups
    const uvec4* eb4 = (const uvec4*)(eb + rs);
    unsigned i = tid;
    bool have = i < ng;
    uvec4 cur = {};
    if (have) cur = __builtin_nontemporal_load(eb4 + i);
    while (have) {
        unsigned in2 = i + BBLOCK;
        bool hn = in2 < ng;
        uvec4 nxt = {};
        if (hn) nxt = __builtin_nontemporal_load(eb4 + in2);
        __builtin_amdgcn_sched_barrier(0);
        vfloat2 a0 = pts[0][cur.x & (PART_SIZE - 1u)], b0 = pts[1][(cur.x >> PART_SHIFT) & (PART_SIZE - 1u)];
        vfloat2 a1 = pts[0][cur.y & (PART_SIZE - 1u)], b1 = pts[1][(cur.y >> PART_SHIFT) & (PART_SIZE - 1u)];
        vfloat2 a2 = pts[0][cur.z & (PART_SIZE - 1u)], b2 = pts[1][(cur.z >> PART_SHIFT) & (PART_SIZE - 1u)];
        vfloat2 a3 = pts[0][cur.w & (PART_SIZE - 1u)], b3 = pts[1][(cur.w >> PART_SHIFT) & (PART_SIZE - 1u)];
        if (cur.x != SENTINEL) local += quad_xy(a0, b0);
        if (cur.y != SENTINEL) local += quad_xy(a1, b1);
        if (cur.z != SENTINEL) local += quad_xy(a2, b2);
        if (cur.w != SENTINEL) local += quad_xy(a3, b3);
        cur = nxt;
        i = in2;
        have = hn;
    }
    for (unsigned j = rs + (ng << 2) + tid; j < re; j += BBLOCK) {   // tail (half==1 only)
        unsigned v = eb[j];
        if (v != SENTINEL)
            local += quad_xy(pts[0][v & (PART_SIZE - 1u)],
                             pts[1][(v >> PART_SHIFT) & (PART_SIZE - 1u)]);
    }
    if (half) {
        for (unsigned j = tid; j < hi; j += BBLOCK) {   // overflow (top) region
            unsigned v = eb[bincap - 1 - (int)j];
            local += quad_xy(pts[0][v & (PART_SIZE - 1u)],
                             pts[1][(v >> PART_SHIFT) & (PART_SIZE - 1u)]);
        }
    }
    double tot = block_reduce(local, sh);
    if (tid == 0) prox_partials[blockIdx.x] = tot;
}

// -------- fallback gather path (verified round-1 kernel, unchanged) --------
#define GATHER8(dsta, i0, i1)                                                   \
    dsta[0] = llvm_amdgcn_raw_buffer_load_v2f32(srd, (i0).x << SHIFT, 0, 1);    \
    dsta[1] = llvm_amdgcn_raw_buffer_load_v2f32(srd, (i0).y << SHIFT, 0, 1);    \
    dsta[2] = llvm_amdgcn_raw_buffer_load_v2f32(srd, (i0).z << SHIFT, 0, 1);    \
    dsta[3] = llvm_amdgcn_raw_buffer_load_v2f32(srd, (i0).w << SHIFT, 0, 1);    \
    dsta[4] = llvm_amdgcn_raw_buffer_load_v2f32(srd, (i1).x << SHIFT, 0, 1);    \
    dsta[5] = llvm_amdgcn_raw_buffer_load_v2f32(srd, (i1).y << SHIFT, 0, 1);    \
    dsta[6] = llvm_amdgcn_raw_buffer_load_v2f32(srd, (i1).z << SHIFT, 0, 1);    \
    dsta[7] = llvm_amdgcn_raw_buffer_load_v2f32(srd, (i1).w << SHIFT, 0, 1);

template <int COMPACT>
__global__ __launch_bounds__(BLOCK) void edge_kernel(const vint4* __restrict__ src4,
                                                     const vint4* __restrict__ dst4, int nvec,
                                                     const int* __restrict__ src,
                                                     const int* __restrict__ dst, int E,
                                                     const void* __restrict__ xy, int N,
                                                     double* __restrict__ prox_partials) {
    __shared__ double sh[16];
    double local = 0.0;
    int tid = blockIdx.x * BLOCK + threadIdx.x;
    const int gstride = EDGE_BLOCKS * BLOCK;
    const int SHIFT = COMPACT ? 3 : 9;

    vint4 srd = make_srd(xy, COMPACT ? (unsigned int)N * 8u : (unsigned int)N * 512u);

    int nvec2 = nvec / 2;
    int v0 = tid;
    bool p0 = v0 < nvec2;
    int v1 = v0 + gstride;
    bool p1 = v1 < nvec2;

    vint4 is0 = {}, is1 = {}, id0 = {}, id1 = {};
    vfloat2 ca[8] = {}, cb[8] = {};
    vfloat2 na[8] = {}, nb[8] = {};

    if (p0) {
        vint4 s0 = __builtin_nontemporal_load(src4 + 2 * (long)v0);
        vint4 s1 = __builtin_nontemporal_load(src4 + 2 * (long)v0 + 1);
        vint4 d0 = __builtin_nontemporal_load(dst4 + 2 * (long)v0);
        vint4 d1 = __builtin_nontemporal_load(dst4 + 2 * (long)v0 + 1);
        GATHER8(ca, s0, s1);
        GATHER8(cb, d0, d1);
    }
    if (p1) {
        is0 = __builtin_nontemporal_load(src4 + 2 * (long)v1);
        is1 = __builtin_nontemporal_load(src4 + 2 * (long)v1 + 1);
        id0 = __builtin_nontemporal_load(dst4 + 2 * (long)v1);
        id1 = __builtin_nontemporal_load(dst4 + 2 * (long)v1 + 1);
    }

    while (p0) {
        if (p1) {
            GATHER8(na, is0, is1);
            GATHER8(nb, id0, id1);
        }
        int v2 = v1 + gstride;
        bool p2 = v2 < nvec2;
        if (p2) {
            is0 = __builtin_nontemporal_load(src4 + 2 * (long)v2);
            is1 = __builtin_nontemporal_load(src4 + 2 * (long)v2 + 1);
            id0 = __builtin_nontemporal_load(dst4 + 2 * (long)v2);
            id1 = __builtin_nontemporal_load(dst4 + 2 * (long)v2 + 1);
        }
        __builtin_amdgcn_sched_barrier(0);
#pragma unroll
        for (int i = 0; i < 8; ++i) local += quad_xy(ca[i], cb[i]);
#pragma unroll
        for (int i = 0; i < 8; ++i) { ca[i] = na[i]; cb[i] = nb[i]; }
        p0 = p1;
        v1 = v2;
        p1 = p2;
    }

    for (int e = 8 * nvec2 + tid; e < E; e += gstride) {
        vfloat2 a = llvm_amdgcn_raw_buffer_load_v2f32(srd, src[e] << SHIFT, 0, 1);
        vfloat2 b = llvm_amdgcn_raw_buffer_load_v2f32(srd, dst[e] << SHIFT, 0, 1);
        local += quad_xy(a, b);
    }
    double tot = block_reduce(local, sh);
    if (threadIdx.x == 0) prox_partials[blockIdx.x] = tot;
}

// Sum partials + spread over first min(10,E) edges + combine. One block of 256.
__global__ __launch_bounds__(BLOCK) void finalize_kernel(const int* __restrict__ src,
                                                         const int* __restrict__ dst,
                                                         const float* __restrict__ z,
                                                         const double* __restrict__ prox_partials,
                                                         int nprox,
                                                         const double* __restrict__ comp_partials,
                                                         int ncomp,
                                                         float* __restrict__ out, int N, int E) {
    __shared__ double sh[16];
    int t = threadIdx.x;

    double pl = 0.0;
    for (int i = t; i < nprox; i += BLOCK) pl += prox_partials[i];
    double prox = block_reduce(pl, sh);

    double cl = 0.0;
    for (int i = t; i < ncomp; i += BLOCK) cl += comp_partials[i];
    double comp = block_reduce(cl, sh);

    int n_sp = E < 10 ? E : 10;
    double sl = 0.0;
    if (t < n_sp) {
        int s = src[t], d = dst[t];
        double xa = z[(size_t)s * ZDIM], ya = z[(size_t)s * ZDIM + 1];
        double xb = z[(size_t)d * ZDIM], yb = z[(size_t)d * ZDIM + 1];
        double aa = -(ya * ya + xa * xa);
        double bb = -(yb * yb + xb * xb);
        double ab = -(ya * yb + xa * xb);
        double den = aa * bb;
        sl = (ab * ab - den) / safe_den(den);
    }
    double spread = block_reduce(sl, sh);

    if (t == 0) {
        double loss = prox / (double)E + comp / (double)N;
        if (n_sp > 0) loss += 0.1 * (spread / (double)n_sp);
        out[0] = (float)loss;
    }
}

// ---------------- launch ----------------

extern "C" void kernel_launch(void* const* d_in, const int* in_sizes, int n_in,
                              void* d_out, int out_size, void* d_ws, size_t ws_size,
                              hipStream_t stream) {
    const float* z = (const float*)d_in[0];
    const int* edge_index = (const int*)d_in[1];
    float* out = (float*)d_out;

    const int N = in_sizes[0] / ZDIM;
    const int E = in_sizes[1] / 2;
    const int* src = edge_index;
    const int* dst = edge_index + (size_t)E;

    double* prox_partials = (double*)((char*)d_ws + PROX_OFF);
    double* comp_partials = (double*)((char*)d_ws + COMP_OFF);
    unsigned* gcur = (unsigned*)((char*)d_ws + GCUR_OFF);
    vfloat2* table = (vfloat2*)((char*)d_ws + TABLE_OFF);
    bool use_table = ws_size >= TABLE_OFF + (size_t)N * sizeof(vfloat2);

    // binned-path feasibility (ws-adaptive bincap)
    const int P = (N + PART_SIZE - 1) >> PART_SHIFT;
    const int nbins = P * P;
    size_t gbins_off = TABLE_OFF + (((size_t)N * 8 + 255) & ~(size_t)255);
    bool use_binned = false;
    unsigned* gbins = nullptr;
    int bincap = 0;
    if (use_table && P >= 1 && P <= P_MAX && nbins <= NBINS_MAX && E > nbins * 64 &&
        ws_size > gbins_off) {
        int mean = E / nbins;
        // bottom needs: mean + expected sentinel pads (256 blocks * ~8 = 2048, sigma~74)
        //               + bin-count sigma (~143); OVGUARD top region as backstop
        int cap_want = (mean + 4608 + OVGUARD + 31) & ~31;
        int need_min = mean + 3072 + OVGUARD;
        size_t avail = ws_size - gbins_off;
        int cap_fit = (int)((avail / ((size_t)nbins * 4)) & ~(size_t)31);
        bincap = cap_fit < cap_want ? cap_fit : cap_want;
        if (bincap >= need_min) {
            use_binned = true;
            gbins = (unsigned*)((char*)d_ws + gbins_off);
        }
    }

    if (use_binned) {
        hipMemsetAsync(gcur, 0, (size_t)2 * nbins * GPAD * sizeof(unsigned), stream);
        scatter_kernel<<<SCAT_BLOCKS, SBLOCK, 0, stream>>>(z, table, comp_partials, N,
                                                           src, dst, E, P, nbins, gcur,
                                                           gbins, bincap);
        binned_edge_kernel<<<2 * nbins, BBLOCK, 0, stream>>>(table, N, P, gcur, gbins, bincap,
                                                             prox_partials);
        finalize_kernel<<<1, BLOCK, 0, stream>>>(src, dst, z, prox_partials, 2 * nbins,
                                                 comp_partials, SCAT_BLOCKS,
                                                 out, N, E);
    } else {
        node_kernel<<<NODE_BLOCKS, BLOCK, 0, stream>>>(z, use_table ? table : nullptr,
                                                       comp_partials, N);
        int nvec = E / 4;
        if (use_table) {
            edge_kernel<1><<<EDGE_BLOCKS, BLOCK, 0, stream>>>((const vint4*)src,
                                                              (const vint4*)dst, nvec, src, dst,
                                                              E, table, N, prox_partials);
        } else {
            edge_kernel<0><<<EDGE_BLOCKS, BLOCK, 0, stream>>>((const vint4*)src,
                                                              (const vint4*)dst, nvec, src, dst,
                                                              E, z, N, prox_partials);
        }
        finalize_kernel<<<1, BLOCK, 0, stream>>>(src, dst, z, prox_partials, EDGE_BLOCKS,
                                                 comp_partials, NODE_BLOCKS, out, N, E);
    }
}

// Round 7
// 267.678 us; speedup vs baseline: 1.7449x; 1.0534x over previous
//
#include <hip/hip_runtime.h>
#include <hip/hip_bf16.h>

#define UHG_EPS 1e-9
#define ZDIM 128

#define EDGE_BLOCKS 1024   // fallback gather path
#define NODE_BLOCKS 1024   // fallback only
#define BLOCK 256

// ---- binned path geometry ----
#define PART_SHIFT 13               // 8192 nodes per partition (64 KB of float2)
#define PART_SIZE (1 << PART_SHIFT)
#define P_MAX 25                    // 25*8192 = 204800 >= 200000
#define NBINS_MAX (P_MAX * P_MAX)   // 625
#define RING 48                     // ring slots per bin (three 64B segments)
#define CHUNK 32                    // steady flush: 32 u32 = 128 B (2 HBM lines, 1 atomic)
#define FCHUNK 16                   // final-residue flush granularity: 64 B
#define SCAT_BLOCKS 256             // 1 block/CU
#define SBLOCK 1024                 // 16 waves/block = 16 waves/CU
#define BBLOCK 1024                 // binned-edge block: 16 waves
#define SENTINEL 0xFFFFFFFFu
#define OVGUARD 1024                // overflow entries per bin (top region)
#define GPAD 16                     // u32 stride between cursors (one 64B line each)

// ws layout:
//   [0      , 16 KB ) : double prox partials (2*nbins or EDGE_BLOCKS entries)
//   [16 KB  , 32 KB ) : double comp partials (SCAT_BLOCKS or NODE_BLOCKS)
//   [32 KB  , 112 KB) : u32 cursors, line-padded: bottom[b]=gcur[b*16], top[b]=gcur[(nbins+b)*16]
//   [128 KB , +N*8  ) : float2 table[N] (compact x,y per node)
//   [ ...           ) : u32 gbins[nbins][bincap] (routed packed edges)
#define PROX_OFF 0
#define COMP_OFF (16 * 1024)
#define GCUR_OFF (32 * 1024)
#define TABLE_OFF (128 * 1024)

typedef float vfloat2 __attribute__((ext_vector_type(2)));
typedef int vint4 __attribute__((ext_vector_type(4)));
typedef unsigned uvec4 __attribute__((ext_vector_type(4)));

// CK-style asm-declared buffer load (fallback gather path).
__device__ vfloat2 llvm_amdgcn_raw_buffer_load_v2f32(vint4 rsrc, int voffset, int soffset,
                                                     int cpol) __asm("llvm.amdgcn.raw.buffer.load.v2f32");

__device__ __forceinline__ vint4 make_srd(const void* base, unsigned int bytes) {
    union { const void* p; unsigned int w[2]; } pb;
    pb.p = base;
    vint4 r;
    r.x = (int)pb.w[0];
    r.y = (int)pb.w[1];
    r.z = (int)bytes;
    r.w = 0x00020000;
    return r;
}

// ---------------- device helpers ----------------

__device__ __forceinline__ double safe_den(double den) {
    return copysign(fmax(fabs(den), UHG_EPS), den);
}

__device__ __forceinline__ double quad_xy(vfloat2 a, vfloat2 b) {
    double xa = a.x, ya = a.y, xb = b.x, yb = b.y;
    double aa = 1.0 - (xa * xa + ya * ya);
    double bb = 1.0 - (xb * xb + yb * yb);
    double ab = 1.0 - (xa * xb + ya * yb);
    double den = aa * bb;
    double num = ab * ab - den;
    return num / safe_den(den);
}

__device__ __forceinline__ double wave_reduce(double v) {
    v += __shfl_down(v, 32);
    v += __shfl_down(v, 16);
    v += __shfl_down(v, 8);
    v += __shfl_down(v, 4);
    v += __shfl_down(v, 2);
    v += __shfl_down(v, 1);
    return v;
}

// Block reduction for up to 16 waves: returns total on thread 0. sh >= 16 doubles.
__device__ __forceinline__ double block_reduce(double v, double* sh) {
    int lane = threadIdx.x & 63;
    int wid = threadIdx.x >> 6;
    v = wave_reduce(v);
    if (lane == 0) sh[wid] = v;
    __syncthreads();
    double r = 0.0;
    if (wid == 0) {
        int nw = (int)(blockDim.x >> 6);
        r = (lane < nw) ? sh[lane] : 0.0;
        r += __shfl_down(r, 8);
        r += __shfl_down(r, 4);
        r += __shfl_down(r, 2);
        r += __shfl_down(r, 1);
    }
    __syncthreads();
    return r;
}

// ---------------- kernels ----------------

// Fallback-path node kernel (binned path builds the table inside scatter_kernel).
__global__ __launch_bounds__(BLOCK) void node_kernel(const float* __restrict__ z,
                                                     vfloat2* __restrict__ table,
                                                     double* __restrict__ comp_partials, int N) {
    __shared__ double sh[16];
    const vfloat2* zp = (const vfloat2*)z;
    double local = 0.0;
    for (int i = blockIdx.x * BLOCK + threadIdx.x; i < N; i += NODE_BLOCKS * BLOCK) {
        vfloat2 v = zp[(size_t)i * (ZDIM / 2)];
        if (table) table[i] = v;
        double x = v.x, y = v.y;
        double aa = 1.0 - (x * x + y * y);
        local += (1.0 - aa) / safe_den(aa);   // ab=1, bb=1 against origin
    }
    double tot = block_reduce(local, sh);
    if (threadIdx.x == 0) comp_partials[blockIdx.x] = tot;
}

// Phase A v6 = r6's verified batch-synchronous ring structure with 128B flushes.
// Rationale (r6 post-mortem): E/CHUNK global cursor atomics are serialized per
// cursor across 8 XCDs (~1280 RMWs/cursor at 64B chunks = the invariant ~80us).
// CHUNK 16->32 halves the per-cursor chain AND doubles DRAM burst size. RING=48
// (mod-48 ring, sstart in {0,16,32}); steady flush reads two aligned 64B segments
// per 128B chunk with ONE cursor atomic; final residues flush at 64B granularity
// (FCHUNK) so sentinel-pad capacity cost stays at r6's level.
__global__ __launch_bounds__(SBLOCK) void scatter_kernel(const float* __restrict__ z,
                                                         vfloat2* __restrict__ table,
                                                         double* __restrict__ comp_partials,
                                                         int N,
                                                         const int* __restrict__ src,
                                                         const int* __restrict__ dst, int E,
                                                         int P, int nbins,
                                                         unsigned* __restrict__ gcur,
                                                         unsigned* __restrict__ gbins,
                                                         int bincap) {
    __shared__ unsigned cnt[NBINS_MAX];                        // 2.5 KB
    __shared__ unsigned sstart[NBINS_MAX];                     // 2.5 KB
    __shared__ __align__(16) unsigned stage[NBINS_MAX][RING];  // 120 KB
    __shared__ double sh[16];
    const int tid = threadIdx.x;
    const unsigned botlim = (unsigned)(bincap - OVGUARD);

    for (int b = tid; b < nbins; b += SBLOCK) {
        cnt[b] = 0u;
        sstart[b] = 0u;
    }
    __syncthreads();

    // ---- fused table build + compactness partial (replaces node_kernel) ----
    {
        const vfloat2* zp = (const vfloat2*)z;
        long n0 = (long)blockIdx.x * N / SCAT_BLOCKS;
        long n1 = (long)(blockIdx.x + 1) * N / SCAT_BLOCKS;
        double comp = 0.0;
        for (long i = n0 + tid; i < n1; i += SBLOCK) {
            vfloat2 v = zp[(size_t)i * (ZDIM / 2)];
            table[i] = v;
            double x = v.x, y = v.y;
            double aa = 1.0 - (x * x + y * y);
            comp += (1.0 - aa) / safe_den(aa);
        }
        double tot = block_reduce(comp, sh);   // contains 2 __syncthreads (uniform)
        if (tid == 0) comp_partials[blockIdx.x] = tot;
    }

    auto ovf = [&](int b, unsigned v) {
        unsigned hp = atomicAdd(&gcur[(size_t)(nbins + b) * GPAD], 1u);
        if (hp < (unsigned)OVGUARD)
            gbins[(size_t)b * bincap + (bincap - 1 - (int)hp)] = v;
    };

    // write one aligned 64B segment (16 slots starting at s, s in {0,16,32})
    auto write_seg16 = [&](int b, unsigned s, unsigned* out) {
        const unsigned* sp = &stage[b][s];
        *(uvec4*)(out + 0) = *(const uvec4*)(sp + 0);
        *(uvec4*)(out + 4) = *(const uvec4*)(sp + 4);
        *(uvec4*)(out + 8) = *(const uvec4*)(sp + 8);
        *(uvec4*)(out + 12) = *(const uvec4*)(sp + 12);
    };
    auto ovf_seg16 = [&](int b, unsigned s, unsigned cnt16) {
        for (unsigned j = 0; j < cnt16; ++j) ovf(b, stage[b][s + j]);
    };

    // Flush: each of the first nbins threads owns one bin. Ring => copy-free.
    auto flush_bins = [&](bool final_pad) {
        int b = tid;
        if (b < nbins) {
            unsigned n = cnt[b];
            unsigned st = sstart[b];
            unsigned m = n < (unsigned)RING ? n : (unsigned)RING;  // extras already ovf'd
            while (m >= (unsigned)CHUNK) {                         // 128B, one atomic
                unsigned s0 = st;
                unsigned s1 = st + 16 >= (unsigned)RING ? st + 16 - RING : st + 16;
                unsigned pos = atomicAdd(&gcur[(size_t)b * GPAD], (unsigned)CHUNK);
                if (pos + CHUNK <= botlim) {
                    unsigned* out = gbins + (size_t)b * bincap + pos;
                    write_seg16(b, s0, out);
                    write_seg16(b, s1, out + 16);
                } else {
                    ovf_seg16(b, s0, 16u);
                    ovf_seg16(b, s1, 16u);
                }
                st = st + 32 >= (unsigned)RING ? st + 32 - RING : st + 32;
                m -= (unsigned)CHUNK;
            }
            if (final_pad) {
                while (m >= (unsigned)FCHUNK) {                    // full 64B, no pad
                    unsigned pos = atomicAdd(&gcur[(size_t)b * GPAD], (unsigned)FCHUNK);
                    if (pos + FCHUNK <= botlim) {
                        write_seg16(b, st, gbins + (size_t)b * bincap + pos);
                    } else {
                        ovf_seg16(b, st, 16u);
                    }
                    st = st + 16 >= (unsigned)RING ? st + 16 - RING : st + 16;
                    m -= (unsigned)FCHUNK;
                }
                if (m > 0) {                                       // padded 64B
                    for (unsigned j = m; j < (unsigned)FCHUNK; ++j) stage[b][st + j] = SENTINEL;
                    unsigned pos = atomicAdd(&gcur[(size_t)b * GPAD], (unsigned)FCHUNK);
                    if (pos + FCHUNK <= botlim) {
                        write_seg16(b, st, gbins + (size_t)b * bincap + pos);
                    } else {
                        ovf_seg16(b, st, m);
                    }
                    st = st + 16 >= (unsigned)RING ? st + 16 - RING : st + 16;
                    m = 0;
                }
            }
            cnt[b] = m;
            sstart[b] = st;
        }
    };

    // ---- contiguous per-block edge range in vint4 granules ----
    const long nv4 = (long)E / 4;
    long g0 = (long)blockIdx.x * nv4 / SCAT_BLOCKS;
    long g1 = (long)(blockIdx.x + 1) * nv4 / SCAT_BLOCKS;
    const vint4* s4 = (const vint4*)src;
    const vint4* d4 = (const vint4*)dst;
    long nbatch = (g1 - g0 + SBLOCK - 1) / SBLOCK;

    long i = g0 + tid;
    vint4 cs = {}, cd = {};
    if (i < g1) {
        cs = __builtin_nontemporal_load(s4 + i);
        cd = __builtin_nontemporal_load(d4 + i);
    }
    for (long k = 0; k < nbatch; ++k) {
        bool valid = i < g1;
        vint4 s = cs, d = cd;
        long inext = i + SBLOCK;
        if (inext < g1) {   // prefetch next batch before touching LDS
            cs = __builtin_nontemporal_load(s4 + inext);
            cd = __builtin_nontemporal_load(d4 + inext);
        }
        __builtin_amdgcn_sched_barrier(0);
        if (valid) {
            // phase 1: pure VALU + sstart reads
            int bn0 = (s.x >> PART_SHIFT) * P + (d.x >> PART_SHIFT);
            int bn1 = (s.y >> PART_SHIFT) * P + (d.y >> PART_SHIFT);
            int bn2 = (s.z >> PART_SHIFT) * P + (d.z >> PART_SHIFT);
            int bn3 = (s.w >> PART_SHIFT) * P + (d.w >> PART_SHIFT);
            unsigned vl0 = (unsigned)(s.x & (PART_SIZE - 1)) | ((unsigned)(d.x & (PART_SIZE - 1)) << PART_SHIFT);
            unsigned vl1 = (unsigned)(s.y & (PART_SIZE - 1)) | ((unsigned)(d.y & (PART_SIZE - 1)) << PART_SHIFT);
            unsigned vl2 = (unsigned)(s.z & (PART_SIZE - 1)) | ((unsigned)(d.z & (PART_SIZE - 1)) << PART_SHIFT);
            unsigned vl3 = (unsigned)(s.w & (PART_SIZE - 1)) | ((unsigned)(d.w & (PART_SIZE - 1)) << PART_SHIFT);
            unsigned st0 = sstart[bn0], st1 = sstart[bn1], st2 = sstart[bn2], st3 = sstart[bn3];
            // phase 2: back-to-back ds_add_rtn (pipelined returns)
            unsigned sl0 = atomicAdd(&cnt[bn0], 1u);
            unsigned sl1 = atomicAdd(&cnt[bn1], 1u);
            unsigned sl2 = atomicAdd(&cnt[bn2], 1u);
            unsigned sl3 = atomicAdd(&cnt[bn3], 1u);
            // phase 3: ring placement (mod-48; capacity overflow -> top region)
            unsigned p0 = st0 + sl0; if (p0 >= (unsigned)RING) p0 -= (unsigned)RING;
            unsigned p1 = st1 + sl1; if (p1 >= (unsigned)RING) p1 -= (unsigned)RING;
            unsigned p2 = st2 + sl2; if (p2 >= (unsigned)RING) p2 -= (unsigned)RING;
            unsigned p3 = st3 + sl3; if (p3 >= (unsigned)RING) p3 -= (unsigned)RING;
            if (sl0 < (unsigned)RING) stage[bn0][p0] = vl0; else ovf(bn0, vl0);
            if (sl1 < (unsigned)RING) stage[bn1][p1] = vl1; else ovf(bn1, vl1);
            if (sl2 < (unsigned)RING) stage[bn2][p2] = vl2; else ovf(bn2, vl2);
            if (sl3 < (unsigned)RING) stage[bn3][p3] = vl3; else ovf(bn3, vl3);
        }
        __syncthreads();
        flush_bins(false);
        __syncthreads();
        i = inext;
    }
    // global tail edges (E % 4): handled by the last block
    if (blockIdx.x == SCAT_BLOCKS - 1) {
        for (long e = 4 * nv4 + tid; e < E; e += SBLOCK) {
            int s = src[e], d = dst[e];
            int bn = (s >> PART_SHIFT) * P + (d >> PART_SHIFT);
            unsigned vl = (unsigned)(s & (PART_SIZE - 1)) |
                          ((unsigned)(d & (PART_SIZE - 1)) << PART_SHIFT);
            unsigned st = sstart[bn];
            unsigned sl = atomicAdd(&cnt[bn], 1u);
            unsigned p = st + sl; if (p >= (unsigned)RING) p -= (unsigned)RING;
            if (sl < (unsigned)RING) stage[bn][p] = vl; else ovf(bn, vl);
        }
    }
    __syncthreads();
    flush_bins(true);   // drain: 128B chunks, then 64B chunks, then one padded 64B
}

// Phase B v3: TWO blocks per bin (grid 2*nbins = 1250 -> 4.9 rounds over 256 CUs,
// tail idle ~2.5% instead of 23%). Both endpoint partitions in LDS (128 KB);
// uint4 payload stream software-pipelined one iteration ahead. (r4-verified loop;
// chunk-size agnostic: sentinels are skipped individually.)
__global__ __launch_bounds__(BBLOCK) void binned_edge_kernel(const vfloat2* __restrict__ table,
                                                             int N, int P,
                                                             const unsigned* __restrict__ gcur,
                                                             const unsigned* __restrict__ gbins,
                                                             int bincap,
                                                             double* __restrict__ prox_partials) {
    __shared__ vfloat2 pts[2][PART_SIZE];   // 128 KB
    __shared__ double sh[16];
    const int bin = blockIdx.x >> 1;
    const int half = blockIdx.x & 1;
    const int sp = bin / P, dp = bin % P;
    const int tid = threadIdx.x;
    const int nbins = P * P;
    const unsigned botlim = (unsigned)(bincap - OVGUARD);

    for (int j = tid; j < PART_SIZE; j += BBLOCK) {
        int gs = (sp << PART_SHIFT) + j;
        int gd = (dp << PART_SHIFT) + j;
        vfloat2 zv = {0.0f, 0.0f};
        pts[0][j] = (gs < N) ? table[gs] : zv;
        pts[1][j] = (gd < N) ? table[gd] : zv;
    }
    __syncthreads();

    unsigned lo = gcur[(size_t)bin * GPAD];
    if (lo > botlim) lo = botlim;
    unsigned hi = gcur[(size_t)(nbins + bin) * GPAD];
    if (hi > (unsigned)OVGUARD) hi = (unsigned)OVGUARD;
    const unsigned* eb = gbins + (size_t)bin * bincap;

    unsigned h0 = (lo >> 1) & ~3u;                   // 16B-aligned split point
    unsigned rs = half ? h0 : 0u;
    unsigned re = half ? lo : h0;

    double local = 0.0;
    unsigned ng = (re - rs) >> 2;                    // full uint4 groups
    const uvec4* eb4 = (const uvec4*)(eb + rs);
    unsigned i = tid;
    bool have = i < ng;
    uvec4 cur = {};
    if (have) cur = __builtin_nontemporal_load(eb4 + i);
    while (have) {
        unsigned in2 = i + BBLOCK;
        bool hn = in2 < ng;
        uvec4 nxt = {};
        if (hn) nxt = __builtin_nontemporal_load(eb4 + in2);
        __builtin_amdgcn_sched_barrier(0);
        vfloat2 a0 = pts[0][cur.x & (PART_SIZE - 1u)], b0 = pts[1][(cur.x >> PART_SHIFT) & (PART_SIZE - 1u)];
        vfloat2 a1 = pts[0][cur.y & (PART_SIZE - 1u)], b1 = pts[1][(cur.y >> PART_SHIFT) & (PART_SIZE - 1u)];
        vfloat2 a2 = pts[0][cur.z & (PART_SIZE - 1u)], b2 = pts[1][(cur.z >> PART_SHIFT) & (PART_SIZE - 1u)];
        vfloat2 a3 = pts[0][cur.w & (PART_SIZE - 1u)], b3 = pts[1][(cur.w >> PART_SHIFT) & (PART_SIZE - 1u)];
        if (cur.x != SENTINEL) local += quad_xy(a0, b0);
        if (cur.y != SENTINEL) local += quad_xy(a1, b1);
        if (cur.z != SENTINEL) local += quad_xy(a2, b2);
        if (cur.w != SENTINEL) local += quad_xy(a3, b3);
        cur = nxt;
        i = in2;
        have = hn;
    }
    for (unsigned j = rs + (ng << 2) + tid; j < re; j += BBLOCK) {   // tail (half==1 only)
        unsigned v = eb[j];
        if (v != SENTINEL)
            local += quad_xy(pts[0][v & (PART_SIZE - 1u)],
                             pts[1][(v >> PART_SHIFT) & (PART_SIZE - 1u)]);
    }
    if (half) {
        for (unsigned j = tid; j < hi; j += BBLOCK) {   // overflow (top) region
            unsigned v = eb[bincap - 1 - (int)j];
            local += quad_xy(pts[0][v & (PART_SIZE - 1u)],
                             pts[1][(v >> PART_SHIFT) & (PART_SIZE - 1u)]);
        }
    }
    double tot = block_reduce(local, sh);
    if (tid == 0) prox_partials[blockIdx.x] = tot;
}

// -------- fallback gather path (verified round-1 kernel, unchanged) --------
#define GATHER8(dsta, i0, i1)                                                   \
    dsta[0] = llvm_amdgcn_raw_buffer_load_v2f32(srd, (i0).x << SHIFT, 0, 1);    \
    dsta[1] = llvm_amdgcn_raw_buffer_load_v2f32(srd, (i0).y << SHIFT, 0, 1);    \
    dsta[2] = llvm_amdgcn_raw_buffer_load_v2f32(srd, (i0).z << SHIFT, 0, 1);    \
    dsta[3] = llvm_amdgcn_raw_buffer_load_v2f32(srd, (i0).w << SHIFT, 0, 1);    \
    dsta[4] = llvm_amdgcn_raw_buffer_load_v2f32(srd, (i1).x << SHIFT, 0, 1);    \
    dsta[5] = llvm_amdgcn_raw_buffer_load_v2f32(srd, (i1).y << SHIFT, 0, 1);    \
    dsta[6] = llvm_amdgcn_raw_buffer_load_v2f32(srd, (i1).z << SHIFT, 0, 1);    \
    dsta[7] = llvm_amdgcn_raw_buffer_load_v2f32(srd, (i1).w << SHIFT, 0, 1);

template <int COMPACT>
__global__ __launch_bounds__(BLOCK) void edge_kernel(const vint4* __restrict__ src4,
                                                     const vint4* __restrict__ dst4, int nvec,
                                                     const int* __restrict__ src,
                                                     const int* __restrict__ dst, int E,
                                                     const void* __restrict__ xy, int N,
                                                     double* __restrict__ prox_partials) {
    __shared__ double sh[16];
    double local = 0.0;
    int tid = blockIdx.x * BLOCK + threadIdx.x;
    const int gstride = EDGE_BLOCKS * BLOCK;
    const int SHIFT = COMPACT ? 3 : 9;

    vint4 srd = make_srd(xy, COMPACT ? (unsigned int)N * 8u : (unsigned int)N * 512u);

    int nvec2 = nvec / 2;
    int v0 = tid;
    bool p0 = v0 < nvec2;
    int v1 = v0 + gstride;
    bool p1 = v1 < nvec2;

    vint4 is0 = {}, is1 = {}, id0 = {}, id1 = {};
    vfloat2 ca[8] = {}, cb[8] = {};
    vfloat2 na[8] = {}, nb[8] = {};

    if (p0) {
        vint4 s0 = __builtin_nontemporal_load(src4 + 2 * (long)v0);
        vint4 s1 = __builtin_nontemporal_load(src4 + 2 * (long)v0 + 1);
        vint4 d0 = __builtin_nontemporal_load(dst4 + 2 * (long)v0);
        vint4 d1 = __builtin_nontemporal_load(dst4 + 2 * (long)v0 + 1);
        GATHER8(ca, s0, s1);
        GATHER8(cb, d0, d1);
    }
    if (p1) {
        is0 = __builtin_nontemporal_load(src4 + 2 * (long)v1);
        is1 = __builtin_nontemporal_load(src4 + 2 * (long)v1 + 1);
        id0 = __builtin_nontemporal_load(dst4 + 2 * (long)v1);
        id1 = __builtin_nontemporal_load(dst4 + 2 * (long)v1 + 1);
    }

    while (p0) {
        if (p1) {
            GATHER8(na, is0, is1);
            GATHER8(nb, id0, id1);
        }
        int v2 = v1 + gstride;
        bool p2 = v2 < nvec2;
        if (p2) {
            is0 = __builtin_nontemporal_load(src4 + 2 * (long)v2);
            is1 = __builtin_nontemporal_load(src4 + 2 * (long)v2 + 1);
            id0 = __builtin_nontemporal_load(dst4 + 2 * (long)v2);
            id1 = __builtin_nontemporal_load(dst4 + 2 * (long)v2 + 1);
        }
        __builtin_amdgcn_sched_barrier(0);
#pragma unroll
        for (int i = 0; i < 8; ++i) local += quad_xy(ca[i], cb[i]);
#pragma unroll
        for (int i = 0; i < 8; ++i) { ca[i] = na[i]; cb[i] = nb[i]; }
        p0 = p1;
        v1 = v2;
        p1 = p2;
    }

    for (int e = 8 * nvec2 + tid; e < E; e += gstride) {
        vfloat2 a = llvm_amdgcn_raw_buffer_load_v2f32(srd, src[e] << SHIFT, 0, 1);
        vfloat2 b = llvm_amdgcn_raw_buffer_load_v2f32(srd, dst[e] << SHIFT, 0, 1);
        local += quad_xy(a, b);
    }
    double tot = block_reduce(local, sh);
    if (threadIdx.x == 0) prox_partials[blockIdx.x] = tot;
}

// Sum partials + spread over first min(10,E) edges + combine. One block of 256.
__global__ __launch_bounds__(BLOCK) void finalize_kernel(const int* __restrict__ src,
                                                         const int* __restrict__ dst,
                                                         const float* __restrict__ z,
                                                         const double* __restrict__ prox_partials,
                                                         int nprox,
                                                         const double* __restrict__ comp_partials,
                                                         int ncomp,
                                                         float* __restrict__ out, int N, int E) {
    __shared__ double sh[16];
    int t = threadIdx.x;

    double pl = 0.0;
    for (int i = t; i < nprox; i += BLOCK) pl += prox_partials[i];
    double prox = block_reduce(pl, sh);

    double cl = 0.0;
    for (int i = t; i < ncomp; i += BLOCK) cl += comp_partials[i];
    double comp = block_reduce(cl, sh);

    int n_sp = E < 10 ? E : 10;
    double sl = 0.0;
    if (t < n_sp) {
        int s = src[t], d = dst[t];
        double xa = z[(size_t)s * ZDIM], ya = z[(size_t)s * ZDIM + 1];
        double xb = z[(size_t)d * ZDIM], yb = z[(size_t)d * ZDIM + 1];
        double aa = -(ya * ya + xa * xa);
        double bb = -(yb * yb + xb * xb);
        double ab = -(ya * yb + xa * xb);
        double den = aa * bb;
        sl = (ab * ab - den) / safe_den(den);
    }
    double spread = block_reduce(sl, sh);

    if (t == 0) {
        double loss = prox / (double)E + comp / (double)N;
        if (n_sp > 0) loss += 0.1 * (spread / (double)n_sp);
        out[0] = (float)loss;
    }
}

// ---------------- launch ----------------

extern "C" void kernel_launch(void* const* d_in, const int* in_sizes, int n_in,
                              void* d_out, int out_size, void* d_ws, size_t ws_size,
                              hipStream_t stream) {
    const float* z = (const float*)d_in[0];
    const int* edge_index = (const int*)d_in[1];
    float* out = (float*)d_out;

    const int N = in_sizes[0] / ZDIM;
    const int E = in_sizes[1] / 2;
    const int* src = edge_index;
    const int* dst = edge_index + (size_t)E;

    double* prox_partials = (double*)((char*)d_ws + PROX_OFF);
    double* comp_partials = (double*)((char*)d_ws + COMP_OFF);
    unsigned* gcur = (unsigned*)((char*)d_ws + GCUR_OFF);
    vfloat2* table = (vfloat2*)((char*)d_ws + TABLE_OFF);
    bool use_table = ws_size >= TABLE_OFF + (size_t)N * sizeof(vfloat2);

    // binned-path feasibility (ws-adaptive bincap; same capacity math as r6 —
    // final residues still flush at 64B granularity, so pad cost is unchanged)
    const int P = (N + PART_SIZE - 1) >> PART_SHIFT;
    const int nbins = P * P;
    size_t gbins_off = TABLE_OFF + (((size_t)N * 8 + 255) & ~(size_t)255);
    bool use_binned = false;
    unsigned* gbins = nullptr;
    int bincap = 0;
    if (use_table && P >= 1 && P <= P_MAX && nbins <= NBINS_MAX && E > nbins * 64 &&
        ws_size > gbins_off) {
        int mean = E / nbins;
        int cap_want = (mean + 4608 + OVGUARD + 31) & ~31;
        int need_min = mean + 3072 + OVGUARD;
        size_t avail = ws_size - gbins_off;
        int cap_fit = (int)((avail / ((size_t)nbins * 4)) & ~(size_t)31);
        bincap = cap_fit < cap_want ? cap_fit : cap_want;
        if (bincap >= need_min) {
            use_binned = true;
            gbins = (unsigned*)((char*)d_ws + gbins_off);
        }
    }

    if (use_binned) {
        hipMemsetAsync(gcur, 0, (size_t)2 * nbins * GPAD * sizeof(unsigned), stream);
        scatter_kernel<<<SCAT_BLOCKS, SBLOCK, 0, stream>>>(z, table, comp_partials, N,
                                                           src, dst, E, P, nbins, gcur,
                                                           gbins, bincap);
        binned_edge_kernel<<<2 * nbins, BBLOCK, 0, stream>>>(table, N, P, gcur, gbins, bincap,
                                                             prox_partials);
        finalize_kernel<<<1, BLOCK, 0, stream>>>(src, dst, z, prox_partials, 2 * nbins,
                                                 comp_partials, SCAT_BLOCKS,
                                                 out, N, E);
    } else {
        node_kernel<<<NODE_BLOCKS, BLOCK, 0, stream>>>(z, use_table ? table : nullptr,
                                                       comp_partials, N);
        int nvec = E / 4;
        if (use_table) {
            edge_kernel<1><<<EDGE_BLOCKS, BLOCK, 0, stream>>>((const vint4*)src,
                                                              (const vint4*)dst, nvec, src, dst,
                                                              E, table, N, prox_partials);
        } else {
            edge_kernel<0><<<EDGE_BLOCKS, BLOCK, 0, stream>>>((const vint4*)src,
                                                              (const vint4*)dst, nvec, src, dst,
                                                              E, z, N, prox_partials);
        }
        finalize_kernel<<<1, BLOCK, 0, stream>>>(src, dst, z, prox_partials, EDGE_BLOCKS,
                                                 comp_partials, NODE_BLOCKS, out, N, E);
    }
}